// Round 3
// baseline (602.848 us; speedup 1.0000x reference)
//
#include <hip/hip_runtime.h>
#include <math.h>

// Problem constants
#define BATCH  4
#define LSEQ   2048
#define DMODEL 1024
#define MROWS  (BATCH * LSEQ)   // 8192
#define SCORE_SCALE 8.0f        // sqrt(1024/16), reference MULTIPLIES

#define THREEFRY_PARTITIONABLE 1  // verified correct in round 1

typedef __bf16 bf16_t;
typedef bf16_t bf16x8 __attribute__((ext_vector_type(8)));
typedef bf16_t bf16x4 __attribute__((ext_vector_type(4)));
typedef float  f32x4  __attribute__((ext_vector_type(4)));

#define LDSP(p) ((__attribute__((address_space(3))) void*)(p))
#define GLBP(p) ((const __attribute__((address_space(1))) void*)(p))

// ---------------------------------------------------------------------------
// threefry dropout (verified round 1)
// ---------------------------------------------------------------------------
__device__ __forceinline__ unsigned rotl32(unsigned x, int r) {
    return (x << r) | (x >> (32 - r));
}

__device__ __forceinline__ void threefry2x32(unsigned k0, unsigned k1,
                                             unsigned x0, unsigned x1,
                                             unsigned& o0, unsigned& o1) {
    const unsigned ks0 = k0, ks1 = k1, ks2 = k0 ^ k1 ^ 0x1BD11BDAu;
    x0 += ks0; x1 += ks1;
#define TF_R(r) { x0 += x1; x1 = rotl32(x1, r); x1 ^= x0; }
    TF_R(13) TF_R(15) TF_R(26) TF_R(6)
    x0 += ks1; x1 += ks2 + 1u;
    TF_R(17) TF_R(29) TF_R(16) TF_R(24)
    x0 += ks2; x1 += ks0 + 2u;
    TF_R(13) TF_R(15) TF_R(26) TF_R(6)
    x0 += ks0; x1 += ks1 + 3u;
    TF_R(17) TF_R(29) TF_R(16) TF_R(24)
    x0 += ks1; x1 += ks2 + 4u;
    TF_R(13) TF_R(15) TF_R(26) TF_R(6)
    x0 += ks2; x1 += ks0 + 5u;
#undef TF_R
    o0 = x0; o1 = x1;
}

__device__ __forceinline__ bool dropout_keep(unsigned n) {
    unsigned o0, o1;
#if THREEFRY_PARTITIONABLE
    threefry2x32(0u, 42u, 0u, n, o0, o1);
    unsigned bits = o0 ^ o1;
#else
    const unsigned HALF = (unsigned)(BATCH * LSEQ) * (unsigned)LSEQ / 2u;
    unsigned c0 = (n < HALF) ? n : (n - HALF);
    unsigned c1 = (n < HALF) ? (n + HALF) : n;
    threefry2x32(0u, 42u, c0, c1, o0, o1);
    unsigned bits = (n < HALF) ? o0 : o1;
#endif
    return bits < 0x80000000u;
}

// ---------------------------------------------------------------------------
// Split fp32 -> bf16 hi/lo. grid.y selects input (X0/X1), output offset y*n.
// ---------------------------------------------------------------------------
__global__ __launch_bounds__(256)
void split_f32(const float* __restrict__ X0, const float* __restrict__ X1,
               bf16_t* __restrict__ hi, bf16_t* __restrict__ lo, int n) {
    const int y = blockIdx.y;
    const float* X = y ? X1 : X0;
    long long i = (long long)(blockIdx.x * 256 + threadIdx.x) * 4;
    if (i >= n) return;
    float4 v = *(const float4*)(X + i);
    bf16x4 h, l;
    h[0] = (bf16_t)v.x; l[0] = (bf16_t)(v.x - (float)h[0]);
    h[1] = (bf16_t)v.y; l[1] = (bf16_t)(v.y - (float)h[1]);
    h[2] = (bf16_t)v.z; l[2] = (bf16_t)(v.z - (float)h[2]);
    h[3] = (bf16_t)v.w; l[3] = (bf16_t)(v.w - (float)h[3]);
    *(bf16x4*)(hi + (long long)y * n + i) = h;
    *(bf16x4*)(lo + (long long)y * n + i) = l;
}

// W fp32 [K][N] -> W^T hi/lo bf16 [N][K]; grid.z selects W0/W1, out += z*K*N
__global__ __launch_bounds__(256)
void split_transpose(const float* __restrict__ W0, const float* __restrict__ W1,
                     bf16_t* __restrict__ Th, bf16_t* __restrict__ Tl,
                     int Kd, int Nd) {
    __shared__ float t[32][33];
    const int z = blockIdx.z;
    const float* W = z ? W1 : W0;
    const long long zo = (long long)z * Kd * Nd;
    const int bx = blockIdx.x * 32;  // n
    const int by = blockIdx.y * 32;  // k
    const int tx = threadIdx.x & 31, ty = threadIdx.x >> 5;  // 32x8
#pragma unroll
    for (int i = 0; i < 4; ++i)
        t[ty + i * 8][tx] = W[(long long)(by + ty + i * 8) * Nd + bx + tx];
    __syncthreads();
#pragma unroll
    for (int i = 0; i < 4; ++i) {
        float v = t[tx][ty + i * 8];
        long long idx = zo + (long long)(bx + ty + i * 8) * Kd + by + tx;
        bf16_t h = (bf16_t)v;
        Th[idx] = h;
        Tl[idx] = (bf16_t)(v - (float)h);
    }
}

// bf16 transpose per batch: src [rows][cols] -> dst [cols][rows]
__global__ __launch_bounds__(256)
void transpose_bf16(const bf16_t* __restrict__ src, bf16_t* __restrict__ dst,
                    int rows, int cols) {
    __shared__ bf16_t t[32][33];
    const long long z = blockIdx.z;
    src += z * (long long)rows * cols;
    dst += z * (long long)rows * cols;
    const int bx = blockIdx.x * 32;  // col
    const int by = blockIdx.y * 32;  // row
    const int tx = threadIdx.x & 31, ty = threadIdx.x >> 5;
#pragma unroll
    for (int i = 0; i < 4; ++i)
        t[ty + i * 8][tx] = src[(long long)(by + ty + i * 8) * cols + bx + tx];
    __syncthreads();
#pragma unroll
    for (int i = 0; i < 4; ++i)
        dst[(long long)(bx + ty + i * 8) * rows + by + tx] = t[tx][ty + i * 8];
}

// ---------------------------------------------------------------------------
// MFMA GEMM: C[M,N] = scale * (Ah+Al)[M,K] @ (Bh+Bl)[N,K]^T (+bias)
// TMxTN tile, BK=32, 256 threads = 4 waves arranged WM_ x WN_.
// XOR-swizzled LDS layout: 16B column-group cg of row r lives at LDS slot
// cg ^ ((r>>1)&3). Applied at staging fetch, inverted at fragment read ->
// every quarter-wave ds_read_b128 phase hits all 32 banks exactly 2-way (free).
// SPLIT: 3 MFMAs per product (hi*hi + hi*lo + lo*hi).
// OUT: 0 = fp32*scale, 1 = bf16 hi/lo pair (+bias), 2 = bf16 (+bias)
// bias2: z==1 bias (fused Q/K projections).
// ---------------------------------------------------------------------------
template <int SPLIT, int OUT, int TM, int TN, int WM_, int WN_>
__global__ __launch_bounds__(256)
void gemm_mfma(const bf16_t* __restrict__ Ah, const bf16_t* __restrict__ Al,
               const bf16_t* __restrict__ Bh, const bf16_t* __restrict__ Bl,
               const float* __restrict__ bias, const float* __restrict__ bias2,
               float* __restrict__ Cf, bf16_t* __restrict__ Ch,
               bf16_t* __restrict__ Cl,
               int M, int N, int K, float scale,
               long long sA, long long sB, long long sC) {
    constexpr int TOT = TM + TN;
    constexpr int CHUNKS = TOT / 64;         // 16-row stages per wave
    constexpr int WSM = TM / (WM_ * 16);
    constexpr int WSN = TN / (WN_ * 16);
    __shared__ __align__(16) bf16_t smem[(SPLIT ? 2 : 1) * TOT * 32];
    bf16_t* sAh = smem;
    bf16_t* sBh = smem + TM * 32;
    bf16_t* sAl = SPLIT ? smem + TOT * 32 : nullptr;
    bf16_t* sBl = SPLIT ? smem + TOT * 32 + TM * 32 : nullptr;

    const int tid = threadIdx.x;
    const int lane = tid & 63;
    const int wave = tid >> 6;
    const int quad = lane >> 4;   // 0..3
    const int l16 = lane & 15;
    const int wm = (wave % WM_) * (WSM * 16);
    const int wn = (wave / WM_) * (WSN * 16);
    const long long z = blockIdx.z;
    const int m0 = blockIdx.y * TM, n0 = blockIdx.x * TN;

    const bf16_t* gAh = Ah + z * sA;
    const bf16_t* gBh = Bh + z * sB;
    const bf16_t* gAl = SPLIT ? Al + z * sA : nullptr;
    const bf16_t* gBl = SPLIT ? Bl + z * sB : nullptr;

    // staging lane geometry: 16 rows x 4 column-groups of 16B per round
    const int lrow = lane >> 2;                               // 0..15
    const int scol = ((lane & 3) ^ ((lrow >> 1) & 3)) * 8;    // swizzled fetch col
    // fragment-read swizzle
    const int sw = (l16 >> 1) & 3;

    f32x4 acc[WSM][WSN];
#pragma unroll
    for (int i = 0; i < WSM; ++i)
#pragma unroll
        for (int j = 0; j < WSN; ++j)
            acc[i][j] = (f32x4){0.f, 0.f, 0.f, 0.f};

    for (int k0 = 0; k0 < K; k0 += 32) {
        __syncthreads();  // previous-iter LDS reads done
#pragma unroll
        for (int c = 0; c < CHUNKS; ++c) {
            const int rbase = wave * (TOT / 4) + c * 16;  // multiple of 16
            const int row = rbase + lrow;
            if (rbase < TM) {
                const long long g = (long long)(m0 + row) * K + k0 + scol;
                __builtin_amdgcn_global_load_lds(GLBP(gAh + g), LDSP(sAh + row * 32), 16, 0, 0);
                if constexpr (SPLIT)
                    __builtin_amdgcn_global_load_lds(GLBP(gAl + g), LDSP(sAl + row * 32), 16, 0, 0);
            } else {
                const int br = row - TM;
                const long long g = (long long)(n0 + br) * K + k0 + scol;
                __builtin_amdgcn_global_load_lds(GLBP(gBh + g), LDSP(sBh + br * 32), 16, 0, 0);
                if constexpr (SPLIT)
                    __builtin_amdgcn_global_load_lds(GLBP(gBl + g), LDSP(sBl + br * 32), 16, 0, 0);
            }
        }
        __syncthreads();  // drains vmcnt before fragment reads

        bf16x8 afh[WSM], bfh[WSN];
        bf16x8 afl[WSM], bfl[WSN];
#pragma unroll
        for (int i = 0; i < WSM; ++i) {
            const int ao = (wm + i * 16 + l16) * 32 + (quad ^ sw) * 8;
            afh[i] = *(const bf16x8*)(sAh + ao);
            if constexpr (SPLIT) afl[i] = *(const bf16x8*)(sAl + ao);
        }
#pragma unroll
        for (int j = 0; j < WSN; ++j) {
            const int bo = (wn + j * 16 + l16) * 32 + (quad ^ sw) * 8;
            bfh[j] = *(const bf16x8*)(sBh + bo);
            if constexpr (SPLIT) bfl[j] = *(const bf16x8*)(sBl + bo);
        }
#pragma unroll
        for (int i = 0; i < WSM; ++i)
#pragma unroll
            for (int j = 0; j < WSN; ++j) {
                acc[i][j] = __builtin_amdgcn_mfma_f32_16x16x32_bf16(afh[i], bfh[j], acc[i][j], 0, 0, 0);
                if constexpr (SPLIT) {
                    acc[i][j] = __builtin_amdgcn_mfma_f32_16x16x32_bf16(afh[i], bfl[j], acc[i][j], 0, 0, 0);
                    acc[i][j] = __builtin_amdgcn_mfma_f32_16x16x32_bf16(afl[i], bfh[j], acc[i][j], 0, 0, 0);
                }
            }
    }

    const float* bz = (z == 1 && bias2) ? bias2 : bias;
    // epilogue: D[row=(quad*4+r)][col=l16] per 16x16 subtile
#pragma unroll
    for (int i = 0; i < WSM; ++i)
#pragma unroll
        for (int j = 0; j < WSN; ++j) {
            const int n = n0 + wn + j * 16 + l16;
            float bv = 0.f;
            if constexpr (OUT != 0) bv = bz[n];
#pragma unroll
            for (int r = 0; r < 4; ++r) {
                const int m = m0 + wm + i * 16 + quad * 4 + r;
                const long long idx = z * sC + (long long)m * N + n;
                float v = acc[i][j][r];
                if constexpr (OUT == 0) {
                    Cf[idx] = v * scale;
                } else if constexpr (OUT == 1) {
                    v += bv;
                    bf16_t h = (bf16_t)v;
                    Ch[idx] = h;
                    Cl[idx] = (bf16_t)(v - (float)h);
                } else {
                    v += bv;
                    Ch[idx] = (bf16_t)v;
                }
            }
        }
}

// ---------------------------------------------------------------------------
// Row softmax + dropout: S fp32 (read-only) -> P bf16.
// ---------------------------------------------------------------------------
__global__ __launch_bounds__(256)
void softmax_dropout(const float* __restrict__ S, bf16_t* __restrict__ P) {
    const int LK = LSEQ;
    const unsigned row = blockIdx.x;
    const float* rowp = S + (long long)row * LK;
    bf16_t* prow = P + (long long)row * LK;
    __shared__ float buf[LSEQ];
    __shared__ float rbuf[256];
    const int tid = threadIdx.x;

    float m = -INFINITY;
    for (int j = tid; j < LK; j += 256) {
        float v = rowp[j];
        buf[j] = v;
        m = fmaxf(m, v);
    }
    rbuf[tid] = m;
    __syncthreads();
    for (int s = 128; s > 0; s >>= 1) {
        if (tid < s) rbuf[tid] = fmaxf(rbuf[tid], rbuf[tid + s]);
        __syncthreads();
    }
    m = rbuf[0];
    __syncthreads();

    float l = 0.f;
    for (int j = tid; j < LK; j += 256) {
        float e = expf(buf[j] - m);
        buf[j] = e;
        l += e;
    }
    rbuf[tid] = l;
    __syncthreads();
    for (int s = 128; s > 0; s >>= 1) {
        if (tid < s) rbuf[tid] += rbuf[tid + s];
        __syncthreads();
    }
    l = rbuf[0];

    const float inv = 2.0f / l;  // dropout /0.5 folded in
    for (int j = tid; j < LK; j += 256) {
        unsigned n = row * (unsigned)LK + (unsigned)j;
        float p = dropout_keep(n) ? buf[j] * inv : 0.0f;
        prow[j] = (bf16_t)p;
    }
}

// ---------------------------------------------------------------------------
extern "C" void kernel_launch(void* const* d_in, const int* in_sizes, int n_in,
                              void* d_out, int out_size, void* d_ws, size_t ws_size,
                              hipStream_t stream) {
    const float* query = (const float*)d_in[0];
    const float* key_  = (const float*)d_in[1];
    const float* value = (const float*)d_in[2];
    const float* Wq = (const float*)d_in[3];
    const float* bq = (const float*)d_in[4];
    const float* Wk = (const float*)d_in[5];
    const float* bk = (const float*)d_in[6];
    const float* Wv = (const float*)d_in[7];
    const float* bv = (const float*)d_in[8];
    float* out = (float*)d_out;

    // ws layout (bytes), Q1 = 8192*1024*2 = 16.78MB; total 9*Q1 + 8.4MB = 159.4MB
    char* w = (char*)d_ws;
    const size_t Q1 = (size_t)MROWS * DMODEL * 2;
    bf16_t* Qh  = (bf16_t*)(w);               // [0,2Q1): Qh,Kh  (z-stride)
    bf16_t* Ql  = (bf16_t*)(w + 2 * Q1);      // [2Q1,4Q1): Ql,Kl
    bf16_t* VT  = (bf16_t*)(w + 4 * Q1);      // [4Q1,5Q1)
    float*  S   = (float*)(w + 5 * Q1);       // [5Q1,9Q1) fp32 scores
    // phase-A aliases inside S region:
    bf16_t* XvH = (bf16_t*)(w + 5 * Q1);      // V split hi
    bf16_t* XvL = (bf16_t*)(w + 6 * Q1);      // V split lo
    bf16_t* Vb  = (bf16_t*)(w + 7 * Q1);      // V projected (bf16, row-major)
    bf16_t* XqkH = (bf16_t*)(w + 5 * Q1);     // QK split hi (z-stride)
    bf16_t* XqkL = (bf16_t*)(w + 7 * Q1);     // QK split lo (z-stride)
    bf16_t* WTh = (bf16_t*)(w + 9 * Q1);      // 2x 2.1MB (z-stride D*D)
    bf16_t* WTl = (bf16_t*)(w + 9 * Q1 + 2 * (size_t)DMODEL * DMODEL * 2);
    bf16_t* P   = Qh;  // aliases QhKh region (free after QK^T)

    dim3 b256(256);
    const int NELEM = MROWS * DMODEL;
    const long long DD = (long long)DMODEL * DMODEL;
    dim3 gwt(DMODEL / 32, DMODEL / 32, 1);
    dim3 gwt2(DMODEL / 32, DMODEL / 32, 2);

    // --- V path (Vb scratch in S region dies before S is written)
    split_transpose<<<gwt, b256, 0, stream>>>(Wv, nullptr, WTh, WTl, DMODEL, DMODEL);
    split_f32<<<dim3(NELEM / 1024, 1), b256, 0, stream>>>(value, nullptr, XvH, XvL, NELEM);
    gemm_mfma<1, 2, 64, 128, 1, 4><<<dim3(DMODEL / 128, MROWS / 64, 1), b256, 0, stream>>>(
        XvH, XvL, WTh, WTl, bv, nullptr, nullptr, Vb, nullptr,
        MROWS, DMODEL, DMODEL, 1.f, 0, 0, 0);
    transpose_bf16<<<dim3(DMODEL / 32, LSEQ / 32, BATCH), b256, 0, stream>>>(
        Vb, VT, LSEQ, DMODEL);

    // --- Q and K projections, fused over grid.z
    split_transpose<<<gwt2, b256, 0, stream>>>(Wq, Wk, WTh, WTl, DMODEL, DMODEL);
    split_f32<<<dim3(NELEM / 1024, 2), b256, 0, stream>>>(query, key_, XqkH, XqkL, NELEM);
    gemm_mfma<1, 1, 128, 128, 2, 2><<<dim3(DMODEL / 128, MROWS / 128, 2), b256, 0, stream>>>(
        XqkH, XqkL, WTh, WTl, bq, bk, nullptr, Qh, Ql,
        MROWS, DMODEL, DMODEL, 1.f,
        (long long)NELEM, DD, (long long)NELEM);

    // --- S = 8 * Q K^T (batched)
    gemm_mfma<1, 0, 128, 128, 2, 2><<<dim3(LSEQ / 128, LSEQ / 128, BATCH), b256, 0, stream>>>(
        Qh, Ql, Qh + NELEM, Ql + NELEM, nullptr, nullptr, S, nullptr, nullptr,
        LSEQ, LSEQ, DMODEL, SCORE_SCALE,
        (long long)LSEQ * DMODEL, (long long)LSEQ * DMODEL,
        (long long)LSEQ * LSEQ);

    // --- softmax + dropout -> P bf16 (aliases QhKh region)
    softmax_dropout<<<dim3(MROWS), b256, 0, stream>>>(S, P);

    // --- O = P V (plain bf16), B operand = V^T [D][LK] per batch
    gemm_mfma<0, 0, 64, 128, 1, 4><<<dim3(DMODEL / 128, LSEQ / 64, BATCH), b256, 0, stream>>>(
        P, nullptr, VT, nullptr, nullptr, nullptr, out, nullptr, nullptr,
        LSEQ, DMODEL, LSEQ, 1.f,
        (long long)LSEQ * LSEQ, (long long)DMODEL * LSEQ,
        (long long)LSEQ * DMODEL);
}

// Round 4
// 502.613 us; speedup vs baseline: 1.1994x; 1.1994x over previous
//
#include <hip/hip_runtime.h>
#include <math.h>

// Problem constants
#define BATCH  4
#define LSEQ   2048
#define DMODEL 1024
#define MROWS  (BATCH * LSEQ)   // 8192
#define SCORE_SCALE 8.0f        // sqrt(1024/16), reference MULTIPLIES

#define THREEFRY_PARTITIONABLE 1  // verified correct in round 1

typedef __bf16 bf16_t;
typedef bf16_t bf16x8 __attribute__((ext_vector_type(8)));
typedef bf16_t bf16x4 __attribute__((ext_vector_type(4)));
typedef float  f32x4  __attribute__((ext_vector_type(4)));

#define LDSP(p) ((__attribute__((address_space(3))) void*)(p))
#define GLBP(p) ((const __attribute__((address_space(1))) void*)(p))

// ---------------------------------------------------------------------------
// threefry dropout (verified round 1)
// ---------------------------------------------------------------------------
__device__ __forceinline__ unsigned rotl32(unsigned x, int r) {
    return (x << r) | (x >> (32 - r));
}

__device__ __forceinline__ void threefry2x32(unsigned k0, unsigned k1,
                                             unsigned x0, unsigned x1,
                                             unsigned& o0, unsigned& o1) {
    const unsigned ks0 = k0, ks1 = k1, ks2 = k0 ^ k1 ^ 0x1BD11BDAu;
    x0 += ks0; x1 += ks1;
#define TF_R(r) { x0 += x1; x1 = rotl32(x1, r); x1 ^= x0; }
    TF_R(13) TF_R(15) TF_R(26) TF_R(6)
    x0 += ks1; x1 += ks2 + 1u;
    TF_R(17) TF_R(29) TF_R(16) TF_R(24)
    x0 += ks2; x1 += ks0 + 2u;
    TF_R(13) TF_R(15) TF_R(26) TF_R(6)
    x0 += ks0; x1 += ks1 + 3u;
    TF_R(17) TF_R(29) TF_R(16) TF_R(24)
    x0 += ks1; x1 += ks2 + 4u;
    TF_R(13) TF_R(15) TF_R(26) TF_R(6)
    x0 += ks2; x1 += ks0 + 5u;
#undef TF_R
    o0 = x0; o1 = x1;
}

__device__ __forceinline__ bool dropout_keep(unsigned n) {
    unsigned o0, o1;
#if THREEFRY_PARTITIONABLE
    threefry2x32(0u, 42u, 0u, n, o0, o1);
    unsigned bits = o0 ^ o1;
#else
    const unsigned HALF = (unsigned)(BATCH * LSEQ) * (unsigned)LSEQ / 2u;
    unsigned c0 = (n < HALF) ? n : (n - HALF);
    unsigned c1 = (n < HALF) ? (n + HALF) : n;
    threefry2x32(0u, 42u, c0, c1, o0, o1);
    unsigned bits = (n < HALF) ? o0 : o1;
#endif
    return bits < 0x80000000u;
}

// ---------------------------------------------------------------------------
// Split fp32 -> bf16 hi/lo. grid.y selects input (X0/X1), output offset y*n.
// ---------------------------------------------------------------------------
__global__ __launch_bounds__(256)
void split_f32(const float* __restrict__ X0, const float* __restrict__ X1,
               bf16_t* __restrict__ hi, bf16_t* __restrict__ lo, int n) {
    const int y = blockIdx.y;
    const float* X = y ? X1 : X0;
    long long i = (long long)(blockIdx.x * 256 + threadIdx.x) * 4;
    if (i >= n) return;
    float4 v = *(const float4*)(X + i);
    bf16x4 h, l;
    h[0] = (bf16_t)v.x; l[0] = (bf16_t)(v.x - (float)h[0]);
    h[1] = (bf16_t)v.y; l[1] = (bf16_t)(v.y - (float)h[1]);
    h[2] = (bf16_t)v.z; l[2] = (bf16_t)(v.z - (float)h[2]);
    h[3] = (bf16_t)v.w; l[3] = (bf16_t)(v.w - (float)h[3]);
    *(bf16x4*)(hi + (long long)y * n + i) = h;
    *(bf16x4*)(lo + (long long)y * n + i) = l;
}

// W fp32 [K][N] -> W^T hi/lo bf16 [N][K]; grid.z selects W0/W1, out += z*K*N
__global__ __launch_bounds__(256)
void split_transpose(const float* __restrict__ W0, const float* __restrict__ W1,
                     bf16_t* __restrict__ Th, bf16_t* __restrict__ Tl,
                     int Kd, int Nd) {
    __shared__ float t[32][33];
    const int z = blockIdx.z;
    const float* W = z ? W1 : W0;
    const long long zo = (long long)z * Kd * Nd;
    const int bx = blockIdx.x * 32;  // n
    const int by = blockIdx.y * 32;  // k
    const int tx = threadIdx.x & 31, ty = threadIdx.x >> 5;  // 32x8
#pragma unroll
    for (int i = 0; i < 4; ++i)
        t[ty + i * 8][tx] = W[(long long)(by + ty + i * 8) * Nd + bx + tx];
    __syncthreads();
#pragma unroll
    for (int i = 0; i < 4; ++i) {
        float v = t[tx][ty + i * 8];
        long long idx = zo + (long long)(bx + ty + i * 8) * Kd + by + tx;
        bf16_t h = (bf16_t)v;
        Th[idx] = h;
        Tl[idx] = (bf16_t)(v - (float)h);
    }
}

// ---------------------------------------------------------------------------
// MFMA GEMM: C[M,N] = scale * (Ah+Al)[M,K] @ (Bh+Bl)[N,K]^T (+bias)
// Fixed 128x128 tile, BK=32, 256 threads = 4 waves (2x2), 4x4 subtiles/wave.
// DOUBLE-BUFFERED LDS: loads for iter k+1 issued before MFMA loop of iter k;
// raw s_barrier + manual s_waitcnt vmcnt(G) so the compiler cannot insert a
// full vmcnt(0) drain — the load latency is covered by the MFMA loop.
// XOR-swizzled LDS layout (verified r3: conflicts -> 0).
// SPLIT: 3 MFMAs per product (hi*hi + hi*lo + lo*hi).
// OUT: 0 = fp32*scale, 1 = bf16 hi/lo pair (+bias), 2 = bf16 (+bias)
// BROW: bias indexed by row m (for direct-transposed V projection).
// bias2: z==1 bias (fused Q/K projections).
// ---------------------------------------------------------------------------
template <int SPLIT, int OUT, int BROW>
__global__ __launch_bounds__(256)
void gemm_mfma(const bf16_t* __restrict__ Ah, const bf16_t* __restrict__ Al,
               const bf16_t* __restrict__ Bh, const bf16_t* __restrict__ Bl,
               const float* __restrict__ bias, const float* __restrict__ bias2,
               float* __restrict__ Cf, bf16_t* __restrict__ Ch,
               bf16_t* __restrict__ Cl,
               int M, int N, int K, float scale,
               long long sA, long long sB, long long sC) {
    constexpr int TM = 128, TN = 128, TOT = 256, CHUNKS = 4;
    constexpr int NB = SPLIT ? 2 : 1;           // hi(+lo) planes
    constexpr int BUFSZ = NB * TOT * 32;        // elements per buffer
    __shared__ __align__(16) bf16_t smem[2 * BUFSZ];  // split: 64KB, plain: 32KB

    const int tid = threadIdx.x;
    const int lane = tid & 63;
    const int wave = tid >> 6;
    const int quad = lane >> 4;
    const int l16 = lane & 15;
    const int wm = (wave & 1) * 64;
    const int wn = (wave >> 1) * 64;
    const long long z = blockIdx.z;
    const int m0 = blockIdx.y * TM, n0 = blockIdx.x * TN;

    const bf16_t* gAh = Ah + z * sA;
    const bf16_t* gBh = Bh + z * sB;
    const bf16_t* gAl = SPLIT ? Al + z * sA : nullptr;
    const bf16_t* gBl = SPLIT ? Bl + z * sB : nullptr;

    // staging lane geometry: 16 rows x 4 column-groups of 16B per chunk
    const int lrow = lane >> 2;                               // 0..15
    const int scol = ((lane & 3) ^ ((lrow >> 1) & 3)) * 8;    // swizzled col
    const int sw = (l16 >> 1) & 3;                            // read swizzle

    // issue all staging loads for K-step k0 into buffer b (8 loads split, 4 plain)
    auto issue = [&](int k0, int b) {
        bf16_t* base = smem + b * BUFSZ;
#pragma unroll
        for (int c = 0; c < CHUNKS; ++c) {
            const int rbase = wave * 64 + c * 16;
            const int row = rbase + lrow;
            if (rbase < TM) {
                const long long g = (long long)(m0 + row) * K + k0 + scol;
                __builtin_amdgcn_global_load_lds(GLBP(gAh + g), LDSP(base + row * 32), 16, 0, 0);
                if constexpr (SPLIT)
                    __builtin_amdgcn_global_load_lds(GLBP(gAl + g), LDSP(base + TOT * 32 + row * 32), 16, 0, 0);
            } else {
                const int br = row - TM;
                const long long g = (long long)(n0 + br) * K + k0 + scol;
                __builtin_amdgcn_global_load_lds(GLBP(gBh + g), LDSP(base + TM * 32 + br * 32), 16, 0, 0);
                if constexpr (SPLIT)
                    __builtin_amdgcn_global_load_lds(GLBP(gBl + g), LDSP(base + TOT * 32 + TM * 32 + br * 32), 16, 0, 0);
            }
        }
    };

    f32x4 acc[4][4];
#pragma unroll
    for (int i = 0; i < 4; ++i)
#pragma unroll
        for (int j = 0; j < 4; ++j)
            acc[i][j] = (f32x4){0.f, 0.f, 0.f, 0.f};

    issue(0, 0);
    const int NIT = K >> 5;
    for (int it = 0; it < NIT; ++it) {
        const int b = it & 1;
        const bool more = (it + 1) < NIT;
        if (more) issue((it + 1) << 5, b ^ 1);
        // wait until only the just-issued (next-iter) loads remain in flight
        if constexpr (SPLIT) {
            if (more) asm volatile("s_waitcnt vmcnt(8)" ::: "memory");
            else      asm volatile("s_waitcnt vmcnt(0)" ::: "memory");
        } else {
            if (more) asm volatile("s_waitcnt vmcnt(4)" ::: "memory");
            else      asm volatile("s_waitcnt vmcnt(0)" ::: "memory");
        }
        asm volatile("s_barrier" ::: "memory");  // buf[b] ready for all waves

        bf16_t* base = smem + b * BUFSZ;
        bf16_t* sAh = base;
        bf16_t* sBh = base + TM * 32;
        bf16_t* sAl = base + TOT * 32;
        bf16_t* sBl = base + TOT * 32 + TM * 32;

        bf16x8 afh[4], bfh[4], afl[4], bfl[4];
#pragma unroll
        for (int i = 0; i < 4; ++i) {
            const int ao = (wm + i * 16 + l16) * 32 + (quad ^ sw) * 8;
            afh[i] = *(const bf16x8*)(sAh + ao);
            if constexpr (SPLIT) afl[i] = *(const bf16x8*)(sAl + ao);
        }
#pragma unroll
        for (int j = 0; j < 4; ++j) {
            const int bo = (wn + j * 16 + l16) * 32 + (quad ^ sw) * 8;
            bfh[j] = *(const bf16x8*)(sBh + bo);
            if constexpr (SPLIT) bfl[j] = *(const bf16x8*)(sBl + bo);
        }
#pragma unroll
        for (int i = 0; i < 4; ++i)
#pragma unroll
            for (int j = 0; j < 4; ++j) {
                acc[i][j] = __builtin_amdgcn_mfma_f32_16x16x32_bf16(afh[i], bfh[j], acc[i][j], 0, 0, 0);
                if constexpr (SPLIT) {
                    acc[i][j] = __builtin_amdgcn_mfma_f32_16x16x32_bf16(afh[i], bfl[j], acc[i][j], 0, 0, 0);
                    acc[i][j] = __builtin_amdgcn_mfma_f32_16x16x32_bf16(afl[i], bfh[j], acc[i][j], 0, 0, 0);
                }
            }
        asm volatile("s_barrier" ::: "memory");  // all waves done reading buf[b]
    }

    const float* bz = (z == 1 && bias2) ? bias2 : bias;
    // epilogue: D[row=(quad*4+r)][col=l16] per 16x16 subtile
#pragma unroll
    for (int i = 0; i < 4; ++i)
#pragma unroll
        for (int j = 0; j < 4; ++j) {
            const int n = n0 + wn + j * 16 + l16;
            float bvn = 0.f;
            if constexpr (OUT != 0 && !BROW) bvn = bz[n];
#pragma unroll
            for (int r = 0; r < 4; ++r) {
                const int m = m0 + wm + i * 16 + quad * 4 + r;
                const long long idx = z * sC + (long long)m * N + n;
                float v = acc[i][j][r];
                if constexpr (OUT == 0) {
                    Cf[idx] = v * scale;
                } else if constexpr (OUT == 1) {
                    v += bvn;
                    bf16_t h = (bf16_t)v;
                    Ch[idx] = h;
                    Cl[idx] = (bf16_t)(v - (float)h);
                } else {
                    v += BROW ? bz[m] : bvn;
                    Ch[idx] = (bf16_t)v;
                }
            }
        }
}

// ---------------------------------------------------------------------------
// Row softmax + dropout: S fp32 (read-only) -> P bf16.
// ---------------------------------------------------------------------------
__global__ __launch_bounds__(256)
void softmax_dropout(const float* __restrict__ S, bf16_t* __restrict__ P) {
    const int LK = LSEQ;
    const unsigned row = blockIdx.x;
    const float* rowp = S + (long long)row * LK;
    bf16_t* prow = P + (long long)row * LK;
    __shared__ float buf[LSEQ];
    __shared__ float rbuf[256];
    const int tid = threadIdx.x;

    float m = -INFINITY;
    for (int j = tid; j < LK; j += 256) {
        float v = rowp[j];
        buf[j] = v;
        m = fmaxf(m, v);
    }
    rbuf[tid] = m;
    __syncthreads();
    for (int s = 128; s > 0; s >>= 1) {
        if (tid < s) rbuf[tid] = fmaxf(rbuf[tid], rbuf[tid + s]);
        __syncthreads();
    }
    m = rbuf[0];
    __syncthreads();

    float l = 0.f;
    for (int j = tid; j < LK; j += 256) {
        float e = expf(buf[j] - m);
        buf[j] = e;
        l += e;
    }
    rbuf[tid] = l;
    __syncthreads();
    for (int s = 128; s > 0; s >>= 1) {
        if (tid < s) rbuf[tid] += rbuf[tid + s];
        __syncthreads();
    }
    l = rbuf[0];

    const float inv = 2.0f / l;  // dropout /0.5 folded in
    for (int j = tid; j < LK; j += 256) {
        unsigned n = row * (unsigned)LK + (unsigned)j;
        float p = dropout_keep(n) ? buf[j] * inv : 0.0f;
        prow[j] = (bf16_t)p;
    }
}

// ---------------------------------------------------------------------------
extern "C" void kernel_launch(void* const* d_in, const int* in_sizes, int n_in,
                              void* d_out, int out_size, void* d_ws, size_t ws_size,
                              hipStream_t stream) {
    const float* query = (const float*)d_in[0];
    const float* key_  = (const float*)d_in[1];
    const float* value = (const float*)d_in[2];
    const float* Wq = (const float*)d_in[3];
    const float* bq = (const float*)d_in[4];
    const float* Wk = (const float*)d_in[5];
    const float* bk = (const float*)d_in[6];
    const float* Wv = (const float*)d_in[7];
    const float* bv = (const float*)d_in[8];
    float* out = (float*)d_out;

    // ws layout (bytes), Q1 = 8192*1024*2 = 16.78MB; total 9*Q1 + 8.4MB = 159.4MB
    char* w = (char*)d_ws;
    const size_t Q1 = (size_t)MROWS * DMODEL * 2;
    bf16_t* Qh  = (bf16_t*)(w);               // [0,2Q1): Qh,Kh  (z-stride NELEM)
    bf16_t* Ql  = (bf16_t*)(w + 2 * Q1);      // [2Q1,4Q1): Ql,Kl
    bf16_t* VT  = (bf16_t*)(w + 4 * Q1);      // [4Q1,5Q1): V^T per batch [D][LK]
    float*  S   = (float*)(w + 5 * Q1);       // [5Q1,9Q1) fp32 scores
    // phase-A aliases inside S region:
    bf16_t* XvH  = (bf16_t*)(w + 5 * Q1);     // V split hi
    bf16_t* XvL  = (bf16_t*)(w + 6 * Q1);     // V split lo (unused by GEMM)
    bf16_t* XqkH = (bf16_t*)(w + 5 * Q1);     // QK split hi (z-stride NELEM)
    bf16_t* XqkL = (bf16_t*)(w + 7 * Q1);     // QK split lo (z-stride NELEM)
    bf16_t* WTh = (bf16_t*)(w + 9 * Q1);      // 2 z-slots of D*D
    bf16_t* WTl = (bf16_t*)(w + 9 * Q1 + 2 * (size_t)DMODEL * DMODEL * 2);
    bf16_t* P   = Qh;  // [0,2Q1) aliases Qh+Kh (dead after QK^T)

    dim3 b256(256);
    const int NELEM = MROWS * DMODEL;
    const long long DD = (long long)DMODEL * DMODEL;
    dim3 gwt1(DMODEL / 32, DMODEL / 32, 1);
    dim3 gwt2(DMODEL / 32, DMODEL / 32, 2);

    // --- V path: V^T = Wv^T @ X^T directly (plain bf16, row-bias), no transpose
    split_transpose<<<gwt1, b256, 0, stream>>>(Wv, nullptr, WTh, WTl, DMODEL, DMODEL);
    split_f32<<<dim3(NELEM / 1024, 1), b256, 0, stream>>>(value, nullptr, XvH, XvL, NELEM);
    gemm_mfma<0, 2, 1><<<dim3(LSEQ / 128, DMODEL / 128, BATCH), b256, 0, stream>>>(
        WTh, nullptr, XvH, nullptr, bv, nullptr, nullptr, VT, nullptr,
        DMODEL, LSEQ, DMODEL, 1.f,
        0, (long long)LSEQ * DMODEL, (long long)DMODEL * LSEQ);

    // --- Q and K projections, fused over grid.z (split precision)
    split_transpose<<<gwt2, b256, 0, stream>>>(Wq, Wk, WTh, WTl, DMODEL, DMODEL);
    split_f32<<<dim3(NELEM / 1024, 2), b256, 0, stream>>>(query, key_, XqkH, XqkL, NELEM);
    gemm_mfma<1, 1, 0><<<dim3(DMODEL / 128, MROWS / 128, 2), b256, 0, stream>>>(
        XqkH, XqkL, WTh, WTl, bq, bk, nullptr, Qh, Ql,
        MROWS, DMODEL, DMODEL, 1.f,
        (long long)NELEM, DD, (long long)NELEM);

    // --- S = 8 * Q K^T (batched, split precision)
    gemm_mfma<1, 0, 0><<<dim3(LSEQ / 128, LSEQ / 128, BATCH), b256, 0, stream>>>(
        Qh, Ql, Qh + NELEM, Ql + NELEM, nullptr, nullptr, S, nullptr, nullptr,
        LSEQ, LSEQ, DMODEL, SCORE_SCALE,
        (long long)LSEQ * DMODEL, (long long)LSEQ * DMODEL,
        (long long)LSEQ * LSEQ);

    // --- softmax + dropout -> P bf16 (aliases Qh/Kh region)
    softmax_dropout<<<dim3(MROWS), b256, 0, stream>>>(S, P);

    // --- O = P V (plain bf16), B operand = V^T [D][LK] per batch
    gemm_mfma<0, 0, 0><<<dim3(DMODEL / 128, LSEQ / 128, BATCH), b256, 0, stream>>>(
        P, nullptr, VT, nullptr, nullptr, nullptr, out, nullptr, nullptr,
        LSEQ, DMODEL, LSEQ, 1.f,
        (long long)LSEQ * LSEQ, (long long)DMODEL * LSEQ,
        (long long)LSEQ * DMODEL);
}